// Round 16
// baseline (38.747 us; speedup 1.0000x reference)
//
#include <hip/hip_runtime.h>
#include <hip/hip_bf16.h>

// APLoss (r2d2 QAPLoss). B=2, H=W=32 -> N=M=1024/batch, D=128, 25 bins.
// u = 24*(1-sim); cumsum_k of triangular bins = clamp(k+1-u, 0, 1).
// R16: S0 GEMM on matrix cores. S0 = d1^T d2 computed exactly-enough via
// 3-way bf16 split (x = x1+x2+x3; 6 cross products, err ~2^-26) with
// mfma_f32_16x16x32_bf16. Warp/hist/AP phases unchanged (R15).
//   k_prep : desc1 -> d1s[s][b][n][c] bf16; desc2 -> frag-swizzled d2f
//   k_main : MFMA S0 tile (8q+8pad x 1024p) -> bilinear warp + hist + AP
//   k_final: 256 partials -> out

#define NQB 25

typedef __attribute__((ext_vector_type(8))) short    bf16x8;
typedef __attribute__((ext_vector_type(8))) unsigned short us8;
typedef __attribute__((ext_vector_type(4))) float    f32x4;

// DPP butterfly add over 16-lane rows (pure VALU, no LDS pipe).
template<int CTRL>
__device__ __forceinline__ float dppadd(float v) {
    int s = __builtin_amdgcn_update_dpp(0, __float_as_int(v), CTRL, 0xf, 0xf, true);
    return v + __int_as_float(s);
}
__device__ __forceinline__ float red16(float v) {
    v = dppadd<0xB1>(v);   // quad_perm xor1
    v = dppadd<0x4E>(v);   // quad_perm xor2
    v = dppadd<0x141>(v);  // row_half_mirror = xor7
    v = dppadd<0x140>(v);  // row_mirror      = xor15
    return v;              // every lane: its 16-lane-row sum
}

__device__ __forceinline__ void split3(float x, unsigned short& o1,
                                       unsigned short& o2, unsigned short& o3)
{
    __hip_bfloat16 b1 = __float2bfloat16(x);
    float r = x - __bfloat162float(b1);
    __hip_bfloat16 b2 = __float2bfloat16(r);
    r = r - __bfloat162float(b2);
    __hip_bfloat16 b3 = __float2bfloat16(r);
    o1 = __builtin_bit_cast(unsigned short, b1);
    o2 = __builtin_bit_cast(unsigned short, b2);
    o3 = __builtin_bit_cast(unsigned short, b3);
}

// ---- K0: build bf16-split operands -----------------------------------------
// bid < B*32 : desc1 [b][c][n] -> d1s[s][b][n][c]   (32-n-row tile, LDS transpose)
// else       : desc2 [b][c][p] -> d2f[s][b][pt][kt][lane][8]  (MFMA-frag order)
__global__ __launch_bounds__(256) void k_prep(const float* __restrict__ desc1,
                                              const float* __restrict__ desc2,
                                              unsigned short* __restrict__ d1s,
                                              unsigned short* __restrict__ d2f,
                                              int npos)
{
    __shared__ float t32[32][33];
    __shared__ float tile[128][17];
    int B = npos >> 10;
    int bid = blockIdx.x, tid = threadIdx.x;
    size_t sstride = (size_t)npos * 128;          // ushorts per split plane

    if (bid < B * 32) {
        int b = bid >> 5, n0 = (bid & 31) << 5;
        for (int c0 = 0; c0 < 128; c0 += 32) {
            int i = tid >> 5, j = tid & 31;
#pragma unroll
            for (int r = 0; r < 4; ++r) {
                int cl = i + (r << 3);
                t32[cl][j] = desc1[((size_t)(b * 128 + c0 + cl) << 10) + n0 + j];
            }
            __syncthreads();
            int nl = tid >> 3, cg = tid & 7;
#pragma unroll
            for (int cc = 0; cc < 4; ++cc) {
                int cl = (cg << 2) + cc;
                unsigned short s1, s2, s3;
                split3(t32[cl][nl], s1, s2, s3);
                size_t idx = ((size_t)(b << 10) + n0 + nl) * 128 + c0 + cl;
                d1s[idx] = s1;
                d1s[sstride + idx] = s2;
                d1s[2 * sstride + idx] = s3;
            }
            __syncthreads();
        }
    } else {
        int r2 = bid - B * 32;
        int b = r2 >> 6, pt = r2 & 63;
        int p0 = pt << 4;
#pragma unroll
        for (int it = 0; it < 8; ++it) {
            int c = (tid >> 4) + (it << 4);
            int pp = tid & 15;
            tile[c][pp] = desc2[((size_t)(b * 128 + c) << 10) + p0 + pp];
        }
        __syncthreads();
        int l = tid & 63, kt = tid >> 6;
        us8 o1, o2, o3;
#pragma unroll
        for (int j = 0; j < 8; ++j) {
            int c = (kt << 5) + ((l >> 4) << 3) + j;
            unsigned short s1, s2, s3;
            split3(tile[c][l & 15], s1, s2, s3);
            o1[j] = s1; o2[j] = s2; o3[j] = s3;
        }
        size_t bi = (((size_t)(b * 64 + pt) * 4 + kt) << 6) + l;  // us8 units
        us8* dst = (us8*)d2f;
        size_t s8 = sstride >> 3;
        dst[bi] = o1; dst[s8 + bi] = o2; dst[2 * s8 + bi] = o3;
    }
}

// ---- K1: MFMA S0 GEMM + bilinear warp + histogram + AP ---------------------
// block = 8 q (+8 zero-pad rows) x ALL 1024 p, 512 thr (8 waves).
// Wave w owns p in [w*128, w*128+128): 8 n-tiles x 4 k-steps x 6 products.
__global__ __launch_bounds__(512) void k_main(const unsigned short* __restrict__ d1s,
                                              const unsigned short* __restrict__ d2f,
                                              const float* __restrict__ grd,
                                              const int* __restrict__ label,
                                              float* __restrict__ appart,
                                              int npos)
{
    __shared__ float s[8][1024];    // S0 tile: 8 queries x 1024 grid positions
    __shared__ float CNs[8][4][NQB];
    __shared__ float CRs[8][4][NQB];
    __shared__ float apb[8];

    int tid = threadIdx.x;
    int qg0 = blockIdx.x << 3;      // global query base (b*1024 + n0)
    int b = qg0 >> 10;

    // ---- prefetch labels + grid coords (hide under GEMM) ----
    int q = tid >> 6, l = tid & 63; // hist roles: wave = query, lane = l
    const int* lp = label + ((size_t)(qg0 + q) << 10) + l;
    int lv[16];
#pragma unroll
    for (int e = 0; e < 16; e++) lv[e] = lp[(size_t)(e << 6)];
    const float2* gp = (const float2*)grd + ((size_t)b << 10) + l;
    float2 gv[16];
#pragma unroll
    for (int e = 0; e < 16; e++) gv[e] = gp[(size_t)(e << 6)];

    // ---- MFMA S0 GEMM (3-split bf16, 6 cross products) ----
    int w = q;                      // wave id = p-range owner
    int col = l & 15, kg = l >> 4;  // A-row / D-col, k-group
    size_t s8 = (size_t)npos * 16;  // short8 units per split plane
    const bf16x8* A8 = (const bf16x8*)d1s;
    const bf16x8* B8 = (const bf16x8*)d2f;

    f32x4 acc[8];
#pragma unroll
    for (int nt = 0; nt < 8; ++nt) acc[nt] = (f32x4){0.f, 0.f, 0.f, 0.f};

    bool aval = col < 8;
    size_t abase = ((size_t)(qg0 + (col & 7)) << 4) + kg;      // + kt*4
    size_t bbase = (((size_t)(b << 6) + (w << 3)) << 8) + l;   // + nt*256 + kt*64
    bf16x8 zf = {0, 0, 0, 0, 0, 0, 0, 0};

#pragma unroll
    for (int kt = 0; kt < 4; ++kt) {
        bf16x8 A0 = aval ? A8[abase + (kt << 2)] : zf;
        bf16x8 A1 = aval ? A8[s8 + abase + (kt << 2)] : zf;
        bf16x8 A2 = aval ? A8[2 * s8 + abase + (kt << 2)] : zf;
#pragma unroll
        for (int nt = 0; nt < 8; ++nt) {
            size_t bi = bbase + ((size_t)nt << 8) + (kt << 6);
            bf16x8 B0 = B8[bi];
            bf16x8 B1 = B8[s8 + bi];
            bf16x8 B2 = B8[2 * s8 + bi];
            f32x4 a = acc[nt];
            a = __builtin_amdgcn_mfma_f32_16x16x32_bf16(A0, B0, a, 0, 0, 0);
            a = __builtin_amdgcn_mfma_f32_16x16x32_bf16(A0, B1, a, 0, 0, 0);
            a = __builtin_amdgcn_mfma_f32_16x16x32_bf16(A1, B0, a, 0, 0, 0);
            a = __builtin_amdgcn_mfma_f32_16x16x32_bf16(A0, B2, a, 0, 0, 0);
            a = __builtin_amdgcn_mfma_f32_16x16x32_bf16(A2, B0, a, 0, 0, 0);
            a = __builtin_amdgcn_mfma_f32_16x16x32_bf16(A1, B1, a, 0, 0, 0);
            acc[nt] = a;
        }
    }
    // C/D layout (m89): col = lane&15, row = (lane>>4)*4 + reg. Rows 8-15 = pad.
    if (l < 32) {
        int qh = l >> 4;
#pragma unroll
        for (int nt = 0; nt < 8; ++nt)
#pragma unroll
            for (int r = 0; r < 4; ++r)
                s[(qh << 2) + r][(w << 7) + (nt << 4) + col] = acc[nt][r];
    }
    __syncthreads();

    // ---- histogram with on-the-fly bilinear warp (R15: interior taps) ----
    float CN[NQB], CR[NQB];
#pragma unroll
    for (int k = 0; k < NQB; k++) { CN[k] = 0.f; CR[k] = 0.f; }
    const float* sq = s[q];
#pragma unroll
    for (int e = 0; e < 16; e++) {
        float gx = gv[e].x, gy = gv[e].y;
        float fx = ((gx + 1.f) * 32.f - 1.f) * 0.5f;
        float fy = ((gy + 1.f) * 32.f - 1.f) * 0.5f;
        float x0f = floorf(fx), y0f = floorf(fy);
        float wx1 = fx - x0f, wy1 = fy - y0f;
        float wx0 = 1.f - wx1, wy0 = 1.f - wy1;
        int x0 = (int)x0f, y0 = (int)y0f;
        float w00 = wy0 * wx0;
        float w01 = wy0 * wx1;
        float w10 = wy1 * wx0;
        float w11 = wy1 * wx1;
        int base = (y0 << 5) + x0;
        float2 v0 = *(const float2*)&sq[base];
        float2 v1 = *(const float2*)&sq[base + 32];
        float sv = w00 * v0.x;
        sv = fmaf(w01, v0.y, sv);
        sv = fmaf(w10, v1.x, sv);
        sv = fmaf(w11, v1.y, sv);

        float u = fmaf(-24.f, sv, 24.f);
        float lfv = (float)lv[e];
#pragma unroll
        for (int k = 0; k < NQB; k++) {
            float t = fminf(fmaxf((float)(k + 1) - u, 0.f), 1.f);  // v_med3
            CN[k] += t;
            CR[k] = fmaf(lfv, t, CR[k]);
        }
    }
#pragma unroll
    for (int k = 0; k < NQB; k++) { CN[k] = red16(CN[k]); CR[k] = red16(CR[k]); }
    if ((l & 15) == 0) {
        int rec = l >> 4;
#pragma unroll
        for (int k = 0; k < NQB; k++) { CNs[q][rec][k] = CN[k]; CRs[q][rec][k] = CR[k]; }
    }
    __syncthreads();

    // ---- AP per query (8 threads), block sum -> 1 float ----
    if (tid < 8) {
        float ap = 0.f, prev = 0.f;
#pragma unroll
        for (int k = 0; k < NQB; k++) {
            float cn = CNs[tid][0][k] + CNs[tid][1][k] + CNs[tid][2][k] + CNs[tid][3][k];
            float cr = CRs[tid][0][k] + CRs[tid][1][k] + CRs[tid][2][k] + CRs[tid][3][k];
            float pr = cr / (1e-16f + cn);
            ap += pr * (cr - prev);
            prev = cr;
        }
        apb[tid] = ap / prev;
    }
    __syncthreads();
    if (tid == 0) {
        float v = 0.f;
#pragma unroll
        for (int q2 = 0; q2 < 8; q2++) v += apb[q2];
        appart[blockIdx.x] = v;
    }
}

// ---- K2: final reduce of per-block sums -> d_out ---------------------------
__global__ __launch_bounds__(256) void k_final(const float* __restrict__ appart,
                                               float* __restrict__ out,
                                               int nb, float invn)
{
    int tid = threadIdx.x;
    float v = 0.f;
    for (int i = tid; i < nb; i += 256) v += appart[i];
    for (int off = 32; off; off >>= 1) v += __shfl_xor(v, off, 64);
    __shared__ float wsum[4];
    if ((tid & 63) == 0) wsum[tid >> 6] = v;
    __syncthreads();
    if (tid == 0) out[0] = (wsum[0] + wsum[1] + wsum[2] + wsum[3]) * invn;
}

extern "C" void kernel_launch(void* const* d_in, const int* in_sizes, int n_in,
                              void* d_out, int out_size, void* d_ws, size_t ws_size,
                              hipStream_t stream)
{
    const float* desc1 = (const float*)d_in[0];
    const float* desc2 = (const float*)d_in[1];
    // d_in[2] = reliability: unused by the reference output
    const float* grd   = (const float*)d_in[3];
    const int*   label = (const int*)d_in[4];

    int B = in_sizes[0] / (128 * 1024);
    int npos = B * 1024;
    int nblk = npos / 8;

    char* ws = (char*)d_ws;
    float* appart = (float*)ws;
    size_t off = ((size_t)nblk * 4 + 15) & ~(size_t)15;          // 16B align
    unsigned short* d1s = (unsigned short*)(ws + off);           // 3*npos*128
    unsigned short* d2f = d1s + (size_t)3 * npos * 128;          // 3*npos*128
    float* out = (float*)d_out;

    k_prep<<<B * 96, 256, 0, stream>>>(desc1, desc2, d1s, d2f, npos);
    k_main<<<nblk, 512, 0, stream>>>(d1s, d2f, grd, label, appart, npos);
    k_final<<<1, 256, 0, stream>>>(appart, out, nblk, 1.f / (float)npos);
}

// Round 17
// 25.763 us; speedup vs baseline: 1.5039x; 1.5039x over previous
//
#include <hip/hip_runtime.h>

// APLoss (r2d2 QAPLoss). B=2, H=W=32 -> N=M=1024/batch, D=128, 25 bins.
// u = 24*(1-sim); cumsum_k of triangular bins = clamp(k+1-u, 0, 1).
// R14 champion (25.6us), verbatim re-run to establish the noise band.
// Grid-sample COMMUTES with the GEMM (bilinear warp is linear over channels):
// sim[n][m] = sum_tap w_tap(m) * S0[n][p_tap(m)], S0 = d1^T d2. -> 2 launches:
//   k_main : S0 tile (8q x 1024p, ping-pong GEMM on desc2 directly)
//            -> on-the-fly bilinear warp + histogram + AP  (256 blk x 512 thr)
//   k_final: 256 partials -> out.

#define NQB 25

// DPP butterfly add over 16-lane rows (pure VALU, no LDS pipe).
template<int CTRL>
__device__ __forceinline__ float dppadd(float v) {
    int s = __builtin_amdgcn_update_dpp(0, __float_as_int(v), CTRL, 0xf, 0xf, true);
    return v + __int_as_float(s);
}
__device__ __forceinline__ float red16(float v) {
    v = dppadd<0xB1>(v);   // quad_perm xor1
    v = dppadd<0x4E>(v);   // quad_perm xor2
    v = dppadd<0x141>(v);  // row_half_mirror = xor7
    v = dppadd<0x140>(v);  // row_mirror      = xor15
    return v;              // every lane: its 16-lane-row sum
}

// ---- sim helpers: chunk = 8 consecutive c (verbatim R10, src = desc2) ------
__device__ __forceinline__ void loadc(const float* __restrict__ dp, int ch,
                                      float* d)
{
    int cb = ch << 3;
#pragma unroll
    for (int i = 0; i < 8; i++) {
        d[i]     = dp[(size_t)(cb + i) << 10];           // p = tid
        d[8 + i] = dp[(((size_t)(cb + i)) << 10) + 512]; // p = tid + 512
    }
}
__device__ __forceinline__ void fmac(const float* __restrict__ d1, int ch,
                                     const float* d, float* a0, float* a1)
{
    int cb = ch << 3;
#pragma unroll
    for (int i = 0; i < 8; i++) {
        const float* qp = d1 + ((size_t)(cb + i) << 10);
#pragma unroll
        for (int qq = 0; qq < 8; qq++) {
            float qv = qp[qq];   // wave-uniform -> scalar load
            a0[qq] = fmaf(qv, d[i], a0[qq]);
            a1[qq] = fmaf(qv, d[8 + i], a1[qq]);
        }
    }
}

// ---- K1: fused S0 GEMM + warp + histogram + AP; 8 q x all m, 512 thr -------
__global__ __launch_bounds__(512) void k_main(const float* __restrict__ desc1,
                                              const float* __restrict__ desc2,
                                              const float* __restrict__ grd,
                                              const int* __restrict__ label,
                                              float* __restrict__ appart)
{
    __shared__ float s[8][1024];    // S0 tile: 8 queries x 1024 grid positions
    __shared__ float CNs[8][4][NQB];
    __shared__ float CRs[8][4][NQB];
    __shared__ float apb[8];

    int tid = threadIdx.x;
    int qg0 = blockIdx.x << 3;      // global query base (b*1024 + n0)
    int b = qg0 >> 10;
    int n0 = qg0 & 1023;

    // ---- prefetch labels + grid coords for my 16 m's (hide under GEMM) ----
    int q = tid >> 6, l = tid & 63; // hist roles: wave = query, lane = l
    const int* lp = label + ((size_t)(qg0 + q) << 10) + l;
    int lv[16];
#pragma unroll
    for (int e = 0; e < 16; e++) lv[e] = lp[(size_t)(e << 6)];
    const float2* gp = (const float2*)grd + ((size_t)b << 10) + l;
    float2 gv[16];
#pragma unroll
    for (int e = 0; e < 16; e++) gv[e] = gp[(size_t)(e << 6)];

    // ---- S0 GEMM phase: 2-deep ping-pong over 16 chunks of 8 c ----
    const float* d1 = desc1 + ((size_t)b << 17) + n0;  // q-row: d1[(c<<10)+qq]
    const float* dp = desc2 + ((size_t)b << 17) + tid; // p-col: dp[c<<10]

    float a0[8], a1[8];
#pragma unroll
    for (int qq = 0; qq < 8; qq++) { a0[qq] = 0.f; a1[qq] = 0.f; }

    float dA[16], dB[16];
    loadc(dp, 0, dA);
    for (int ch = 0; ch < 16; ch += 2) {
        loadc(dp, ch + 1, dB);          // issue next chunk
        fmac(d1, ch, dA, a0, a1);       // consume current
        if (ch + 2 < 16) loadc(dp, ch + 2, dA);
        fmac(d1, ch + 1, dB, a0, a1);
    }
#pragma unroll
    for (int qq = 0; qq < 8; qq++) { s[qq][tid] = a0[qq]; s[qq][tid + 512] = a1[qq]; }
    __syncthreads();

    // ---- histogram with on-the-fly bilinear warp of the S0 row ----
    float CN[NQB], CR[NQB];
#pragma unroll
    for (int k = 0; k < NQB; k++) { CN[k] = 0.f; CR[k] = 0.f; }
    const float* sq = s[q];
#pragma unroll
    for (int e = 0; e < 16; e++) {
        float gx = gv[e].x, gy = gv[e].y;
        float fx = ((gx + 1.f) * 32.f - 1.f) * 0.5f;
        float fy = ((gy + 1.f) * 32.f - 1.f) * 0.5f;
        float x0f = floorf(fx), y0f = floorf(fy);
        float wx1 = fx - x0f, wy1 = fy - y0f;
        float wx0 = 1.f - wx1, wy0 = 1.f - wy1;
        int x0 = (int)x0f, y0 = (int)y0f;
        int x1 = x0 + 1, y1 = y0 + 1;
        bool bx0 = (unsigned)x0 < 32u, bx1 = (unsigned)x1 < 32u;
        bool by0 = (unsigned)y0 < 32u, by1 = (unsigned)y1 < 32u;
        float w00 = (by0 && bx0) ? wy0 * wx0 : 0.f;
        float w01 = (by0 && bx1) ? wy0 * wx1 : 0.f;
        float w10 = (by1 && bx0) ? wy1 * wx0 : 0.f;
        float w11 = (by1 && bx1) ? wy1 * wx1 : 0.f;
        int xc0 = min(max(x0, 0), 31), xc1 = min(max(x1, 0), 31);
        int yc0 = min(max(y0, 0), 31), yc1 = min(max(y1, 0), 31);
        float sv = w00 * sq[(yc0 << 5) + xc0];
        sv = fmaf(w01, sq[(yc0 << 5) + xc1], sv);
        sv = fmaf(w10, sq[(yc1 << 5) + xc0], sv);
        sv = fmaf(w11, sq[(yc1 << 5) + xc1], sv);

        float u = fmaf(-24.f, sv, 24.f);
        float lfv = (float)lv[e];
#pragma unroll
        for (int k = 0; k < NQB; k++) {
            float t = fminf(fmaxf((float)(k + 1) - u, 0.f), 1.f);  // v_med3
            CN[k] += t;
            CR[k] = fmaf(lfv, t, CR[k]);
        }
    }
#pragma unroll
    for (int k = 0; k < NQB; k++) { CN[k] = red16(CN[k]); CR[k] = red16(CR[k]); }
    if ((l & 15) == 0) {
        int rec = l >> 4;
#pragma unroll
        for (int k = 0; k < NQB; k++) { CNs[q][rec][k] = CN[k]; CRs[q][rec][k] = CR[k]; }
    }
    __syncthreads();

    // ---- AP per query (8 threads), block sum -> 1 float ----
    if (tid < 8) {
        float ap = 0.f, prev = 0.f;
#pragma unroll
        for (int k = 0; k < NQB; k++) {
            float cn = CNs[tid][0][k] + CNs[tid][1][k] + CNs[tid][2][k] + CNs[tid][3][k];
            float cr = CRs[tid][0][k] + CRs[tid][1][k] + CRs[tid][2][k] + CRs[tid][3][k];
            float pr = cr / (1e-16f + cn);
            ap += pr * (cr - prev);
            prev = cr;
        }
        apb[tid] = ap / prev;
    }
    __syncthreads();
    if (tid == 0) {
        float v = 0.f;
#pragma unroll
        for (int q2 = 0; q2 < 8; q2++) v += apb[q2];
        appart[blockIdx.x] = v;
    }
}

// ---- K2: final reduce of per-block sums -> d_out ---------------------------
__global__ __launch_bounds__(256) void k_final(const float* __restrict__ appart,
                                               float* __restrict__ out,
                                               int nb, float invn)
{
    int tid = threadIdx.x;
    float v = 0.f;
    for (int i = tid; i < nb; i += 256) v += appart[i];
    for (int off = 32; off; off >>= 1) v += __shfl_xor(v, off, 64);
    __shared__ float wsum[4];
    if ((tid & 63) == 0) wsum[tid >> 6] = v;
    __syncthreads();
    if (tid == 0) out[0] = (wsum[0] + wsum[1] + wsum[2] + wsum[3]) * invn;
}

extern "C" void kernel_launch(void* const* d_in, const int* in_sizes, int n_in,
                              void* d_out, int out_size, void* d_ws, size_t ws_size,
                              hipStream_t stream)
{
    const float* desc1 = (const float*)d_in[0];
    const float* desc2 = (const float*)d_in[1];
    // d_in[2] = reliability: unused by the reference output
    const float* grd   = (const float*)d_in[3];
    const int*   label = (const int*)d_in[4];

    int B = in_sizes[0] / (128 * 1024);
    int npos = B * 1024;
    int nblk = npos / 8;

    float* ws = (float*)d_ws;
    float* appart = ws;                 // nblk floats
    float* out = (float*)d_out;

    k_main<<<nblk, 512, 0, stream>>>(desc1, desc2, grd, label, appart);
    k_final<<<1, 256, 0, stream>>>(appart, out, nblk, 1.f / (float)npos);
}